// Round 8
// baseline (1606.710 us; speedup 1.0000x reference)
//
#include <hip/hip_runtime.h>
#include <hip/hip_bf16.h>
#include <stdint.h>

// ---- problem dims (fixed by setup_inputs) ----
#define DIM   4096
#define HID   11008
#define MTOK  4096              // B*S = 2*2048
#define NELW  (HID * DIM)       // 45,088,768 elements per weight matrix

typedef __bf16 bf16x8 __attribute__((ext_vector_type(8)));
typedef float  f32x4  __attribute__((ext_vector_type(4)));
using gptr_t = const __attribute__((address_space(1))) void*;
using lptr_t = __attribute__((address_space(3))) void*;

__device__ __forceinline__ float bf2f(unsigned short u) {
    unsigned int t = ((unsigned int)u) << 16;
    float f; __builtin_memcpy(&f, &t, 4); return f;
}
__device__ __forceinline__ unsigned short f2bf(float f) {   // RNE
    unsigned int x; __builtin_memcpy(&x, &f, 4);
    x += 0x7fffu + ((x >> 16) & 1u);
    return (unsigned short)(x >> 16);
}

__device__ __constant__ float NF4_TAB[16] = {
    -1.0f, -0.6961928009986877f, -0.5250730514526367f, -0.39491748809814453f,
    -0.28444138169288635f, -0.18477343022823334f, -0.09105003625154495f, 0.0f,
    0.07958029955625534f, 0.16093020141124725f, 0.24611230194568634f,
    0.33791524171829224f, 0.44070982933044434f, 0.5626170039176941f,
    0.6989939212799072f, 1.0f};

// dequant 8 codes at element offset `base` (table via wave shfl from lanes 0-15)
__device__ __forceinline__ void dq8(const int* codes, const float* absmax,
                                    unsigned short* out, long base, float tv)
{
    int4 c0 = *(const int4*)(codes + base);
    int4 c1 = *(const int4*)(codes + base + 4);
    float s = absmax[base >> 6];
    union { uint4 q; unsigned short u[8]; } o;
    o.u[0] = f2bf(__shfl(tv, c0.x) * s);
    o.u[1] = f2bf(__shfl(tv, c0.y) * s);
    o.u[2] = f2bf(__shfl(tv, c0.z) * s);
    o.u[3] = f2bf(__shfl(tv, c0.w) * s);
    o.u[4] = f2bf(__shfl(tv, c1.x) * s);
    o.u[5] = f2bf(__shfl(tv, c1.y) * s);
    o.u[6] = f2bf(__shfl(tv, c1.z) * s);
    o.u[7] = f2bf(__shfl(tv, c1.w) * s);
    *(uint4*)(out + base) = o.q;
}

// preamble: blocks [0, 22016) dequant W1; blocks [22016, 30208) cast x->bf16
#define W1BLK 22016
#define PREBLK (W1BLK + (MTOK * DIM) / 2048)
__global__ __launch_bounds__(256) void pre_k(
    const int* __restrict__ w1c, const float* __restrict__ w1a,
    unsigned short* __restrict__ W1,
    const float* __restrict__ x, unsigned short* __restrict__ Xb)
{
    float tv = NF4_TAB[threadIdx.x & 15];
    if ((int)blockIdx.x < W1BLK) {
        long base = ((long)blockIdx.x * 256 + threadIdx.x) * 8;
        dq8(w1c, w1a, W1, base, tv);
    } else {
        long base = ((long)(blockIdx.x - W1BLK) * 256 + threadIdx.x) * 8;
        float4 a = *(const float4*)(x + base);
        float4 b = *(const float4*)(x + base + 4);
        union { uint4 q; unsigned short u[8]; } o;
        o.u[0] = f2bf(a.x); o.u[1] = f2bf(a.y); o.u[2] = f2bf(a.z); o.u[3] = f2bf(a.w);
        o.u[4] = f2bf(b.x); o.u[5] = f2bf(b.y); o.u[6] = f2bf(b.z); o.u[7] = f2bf(b.w);
        *(uint4*)(Xb + base) = o.q;
    }
}

// ============================================================================
// 256x256-tile 4-phase/K-tile GEMM (R5 core), R8: main loop unrolled 2x so
// the double-buffer index is a COMPILE-TIME constant (m201's 8-phase/2-K-tile
// form).  Ledger, issue order, vmcnt placement identical to R5/R7.
// C[m,n] = sum_k A[m,k]*B[n,k]; A:[M,K] bf16, B:[N,K] bf16 row-major.
// 512 thr = 8 waves (2M x 4N); BK=64; LDS 128 KiB (2buf x {A,B} x 2half).
//
// vmcnt LEDGER (r3/r4-verified; 2 loads per STAGE): prologue 12 issues,
// vmcnt(4)+BAR publishes tile0; iter t: ph1 B0[t+1], ph2 B1[t+1], ph3
// A0[t+2] + vmcnt(6) publishes A[t+1], ph4 A1[t+2] + vmcnt(4) publishes
// B[t+1].  In-flight never <4 (T4).  Every ds_read is lgkmcnt-drained by its
// consuming MFMA before the barrier preceding the overwriting STAGE.
// NT is EVEN for all shapes here (64/64/172): tiles 0..NT-3 via the 2x loop,
// tile NT-2 via one static iter (buf 0), tile NT-1 in the epilogue (buf 1).
//
// Blocks >= ngemm run grid-stride NF4 dequant (dqc/dqa->dqo) -- tail fill;
// consumer is the NEXT dispatch (dispatch boundary = fence).
// MODE: 0 = f32 out, 1 = bf16 out, 2 = bf16 fused h=silu(Cout)*acc in-place.
// ============================================================================
template<int MODE>
__global__ __launch_bounds__(512, 2) void gemm256_k(
    const unsigned short* __restrict__ A, const unsigned short* __restrict__ B,
    void* __restrict__ Cout, int M, int N, int K, int ngemm,
    const int* __restrict__ dqc, const float* __restrict__ dqa,
    unsigned short* __restrict__ dqo)
{
    __shared__ __align__(16) unsigned short lds[2][2][2][128 * 64];

    const int tid = threadIdx.x;
    const int lane = tid & 63;

    if ((int)blockIdx.x >= ngemm) {          // ---- tail: grid-stride dequant
        if (!dqo) return;
        const int b = (int)blockIdx.x - ngemm;
        const int ndq = (int)gridDim.x - ngemm;
        const long stride = (long)ndq * 512 * 8;
        float tv = NF4_TAB[lane & 15];
        for (long base = ((long)b * 512 + tid) * 8; base < (long)NELW; base += stride)
            dq8(dqc, dqa, dqo, base, tv);
        return;
    }

    const int w = tid >> 6;
    const int wm = w >> 2, wn = w & 3;           // 2M x 4N wave grid
    const int lrow = lane & 15, hi = lane >> 4;
    const int key = lrow & 7;                    // read-side swizzle key

    const int nbm = M >> 8, nbn = N >> 8;
    const int cpx = (nbm * nbn) >> 3;            // ngemm%8==0 -> bijective
    int swz = ((int)blockIdx.x & 7) * cpx + ((int)blockIdx.x >> 3);
    const int bm = swz % nbm, bn = swz / nbm;    // bm fastest: B-panel reuse

    const long ldK = K;
    const int srow = tid >> 3;                   // 0..63 staging row
    const int scol = ((tid & 7) ^ (srow & 7)) * 8;   // pre-swizzled source col
    const unsigned short* gA = A + ((long)(bm * 256 + srow)) * ldK + scol;
    const unsigned short* gB = B + ((long)(bn * 256 + srow)) * ldK + scol;

    f32x4 acc[8][4];
    #pragma unroll
    for (int m = 0; m < 8; ++m)
        #pragma unroll
        for (int n = 0; n < 4; ++n) acc[m][n] = f32x4{0.f, 0.f, 0.f, 0.f};

    bf16x8 a0[4][2], a1[4][2], b0[2][2], b1[2][2];

    // stage half-tile h (0=A rows0-127, 1=A rows128-255, 2=B0, 3=B1) of K-tile
    auto STAGE = [&](int kt, int h, int b) {
        const unsigned short* src = ((h >> 1) ? gB : gA)
            + (long)((h & 1) * 128) * ldK + (long)kt * 64;
        char* dst = (char*)&lds[b][h >> 1][h & 1][0] + w * 1024;
        __builtin_amdgcn_global_load_lds((gptr_t)src, (lptr_t)dst, 16, 0, 0);
        __builtin_amdgcn_global_load_lds((gptr_t)(src + (long)64 * ldK),
                                         (lptr_t)(dst + 8192), 16, 0, 0);
    };
    // lane's A fragments: which=0 -> rows 0-63 of wave's half, 1 -> rows 64-127
    auto LDA = [&](bf16x8 (&fr)[4][2], int which, int b) {
        const unsigned short* base = &lds[b][0][wm][0];
        #pragma unroll
        for (int m = 0; m < 4; ++m)
            #pragma unroll
            for (int ks = 0; ks < 2; ++ks)
                fr[m][ks] = *(const bf16x8*)(base + (which * 64 + m * 16 + lrow) * 64
                                             + (((ks * 4 + hi) ^ key) * 8));
    };
    // lane's B fragments: which=0 -> n0..1, 1 -> n2..3
    auto LDB = [&](bf16x8 (&fr)[2][2], int which, int b) {
        const unsigned short* base = &lds[b][1][wn >> 1][0];
        #pragma unroll
        for (int n = 0; n < 2; ++n)
            #pragma unroll
            for (int ks = 0; ks < 2; ++ks)
                fr[n][ks] = *(const bf16x8*)(base + ((wn & 1) * 64 + (which * 2 + n) * 16 + lrow) * 64
                                             + (((ks * 4 + hi) ^ key) * 8));
    };
    auto MMA = [&](bf16x8 (&fa)[4][2], bf16x8 (&fb)[2][2], int mo, int no) {
        __builtin_amdgcn_s_setprio(1);
        #pragma unroll
        for (int m = 0; m < 4; ++m)
            #pragma unroll
            for (int n = 0; n < 2; ++n)
                #pragma unroll
                for (int ks = 0; ks < 2; ++ks)
                    acc[mo + m][no + n] = __builtin_amdgcn_mfma_f32_16x16x32_bf16(
                        fa[m][ks], fb[n][ks], acc[mo + m][no + n], 0, 0, 0);
        __builtin_amdgcn_s_setprio(0);
    };
    // s_barrier + sched fence for memory classes (ALU/VALU/SALU/MFMA may cross)
    #define BAR() do { __builtin_amdgcn_s_barrier(); \
                       __builtin_amdgcn_sched_barrier(0xF); } while (0)

    const int NT = K >> 6;
    // one K-tile body; CUR is a compile-time literal at every call site
    #define ITER(t, CUR) do {                                               \
        const int nb_ = (CUR) ^ 1;                                          \
        const int tA_ = ((t) + 2 < NT) ? (t) + 2 : NT - 1;                  \
        /* ph1: B[t] lower frags; issue B0[t+1] */                          \
        STAGE((t) + 1, 2, nb_);                                             \
        LDB(b0, 0, (CUR));                                                  \
        BAR();                                                              \
        MMA(a0, b0, 0, 0);                                                  \
        BAR();                                                              \
        /* ph2: A[t] upper frags; issue B1[t+1] */                          \
        STAGE((t) + 1, 3, nb_);                                             \
        LDA(a1, 1, (CUR));                                                  \
        BAR();                                                              \
        MMA(a1, b0, 4, 0);                                                  \
        BAR();                                                              \
        /* ph3: B[t] upper frags; issue A0[t+2]; publish A[t+1] */          \
        STAGE(tA_, 0, (CUR));                                               \
        LDB(b1, 1, (CUR));                                                  \
        BAR();                                                              \
        MMA(a0, b1, 0, 2);                                                  \
        asm volatile("s_waitcnt vmcnt(6)" ::: "memory");                    \
        BAR();                                                              \
        /* ph4: A[t+1] lower frags from next buf; issue A1[t+2]; publish B */\
        STAGE(tA_, 1, (CUR));                                               \
        LDA(a0, 0, nb_);                                                    \
        BAR();                                                              \
        MMA(a1, b1, 4, 2);                                                  \
        asm volatile("s_waitcnt vmcnt(4)" ::: "memory");                    \
        BAR();                                                              \
    } while (0)

    // ---- prologue: tile0 fully + A-halves of tile1; publish tile0, THEN read
    STAGE(0, 0, 0); STAGE(0, 1, 0); STAGE(0, 2, 0); STAGE(0, 3, 0);
    STAGE(1, 0, 1); STAGE(1, 1, 1);
    asm volatile("s_waitcnt vmcnt(4)" ::: "memory");   // own tile0 loads landed
    BAR();                                             // ...and everyone else's
    LDA(a0, 0, 0);

    // tiles 0..NT-3 (2x-unrolled, static buffer parity), NT even
    for (int t = 0; t + 2 < NT; t += 2) {
        ITER(t, 0);
        ITER(t + 1, 1);
    }
    // tile NT-2 (buf 0, static)
    ITER(NT - 2, 0);
    #undef ITER

    // ---- epilogue: tile NT-1 in buf 1 (static), fully published ----
    LDB(b0, 0, 1);
    MMA(a0, b0, 0, 0);
    LDA(a1, 1, 1);
    MMA(a1, b0, 4, 0);
    LDB(b1, 1, 1);
    MMA(a0, b1, 0, 2);
    MMA(a1, b1, 4, 2);
    #undef BAR

    // ---- C write.  C/D layout: col = lane&15, row = (lane>>4)*4 + reg ----
    const int grow = bm * 256 + wm * 128 + hi * 4;
    const int gcol = bn * 256 + wn * 64 + lrow;
    if (MODE == 0) {
        float* C = (float*)Cout;
        #pragma unroll
        for (int m = 0; m < 8; ++m)
            #pragma unroll
            for (int n = 0; n < 4; ++n)
                #pragma unroll
                for (int r = 0; r < 4; ++r)
                    C[(long)(grow + m * 16 + r) * N + gcol + n * 16] = acc[m][n][r];
    } else if (MODE == 1) {
        unsigned short* C = (unsigned short*)Cout;
        #pragma unroll
        for (int m = 0; m < 8; ++m)
            #pragma unroll
            for (int n = 0; n < 4; ++n)
                #pragma unroll
                for (int r = 0; r < 4; ++r)
                    C[(long)(grow + m * 16 + r) * N + gcol + n * 16] = f2bf(acc[m][n][r]);
    } else {
        // fused SwiGLU: C holds h1 (bf16); acc = h3. write silu(h1)*h3 in place
        unsigned short* C = (unsigned short*)Cout;
        #pragma unroll
        for (int m = 0; m < 8; ++m)
            #pragma unroll
            for (int n = 0; n < 4; ++n)
                #pragma unroll
                for (int r = 0; r < 4; ++r) {
                    long idx = (long)(grow + m * 16 + r) * N + gcol + n * 16;
                    float h1v = bf2f(C[idx]);
                    float g = h1v / (1.0f + __expf(-h1v));
                    C[idx] = f2bf(g * acc[m][n][r]);
                }
    }
}

// ---- workspace layout (bytes) ----
//  [0)          W1 bf16 (90,177,536)
//  [90177536)   W3 bf16 (90,177,536)  -- later reused for W2
//  [180355072)  x  bf16 (33,554,432)
//  [213909504)  h1 bf16 (90,177,536)  -- fused swiglu written in-place by GEMM2
//  total 304,087,040
#define WS_NEEDED 304087040UL
#define DQBLK 512     // tail dequant blocks appended to GEMM1/GEMM2 dispatches

extern "C" void kernel_launch(void* const* d_in, const int* in_sizes, int n_in,
                              void* d_out, int out_size, void* d_ws, size_t ws_size,
                              hipStream_t stream) {
    const float* x   = (const float*)d_in[0];
    const int*   w1c = (const int*)d_in[1];
    const float* w1a = (const float*)d_in[2];
    const int*   w2c = (const int*)d_in[3];
    const float* w2a = (const float*)d_in[4];
    const int*   w3c = (const int*)d_in[5];
    const float* w3a = (const float*)d_in[6];

    if (ws_size < WS_NEEDED) return;   // fail loudly via validation

    char* ws = (char*)d_ws;
    unsigned short* W1 = (unsigned short*)(ws);
    unsigned short* W3 = (unsigned short*)(ws + 90177536);   // also W2 later
    unsigned short* Xb = (unsigned short*)(ws + 180355072);
    unsigned short* H1 = (unsigned short*)(ws + 213909504);

    // preamble: W1 dequant + x cast (one dispatch)
    pre_k<<<PREBLK, 256, 0, stream>>>(w1c, w1a, W1, x, Xb);

    const int g12 = (MTOK / 256) * (HID / 256);   // 688
    const int g3  = (MTOK / 256) * (DIM / 256);   // 256

    // h1 = x @ W1^T; tail blocks dequant W3 -> consumed by NEXT dispatch
    gemm256_k<1><<<g12 + DQBLK, 512, 0, stream>>>(Xb, W1, H1, MTOK, HID, DIM,
                                                  g12, w3c, w3a, W3);
    // h = silu(h1) * (x @ W3^T) in-place; tail blocks dequant W2 into W1's buf
    // (GEMM1 retired at dispatch boundary; this dispatch reads only Xb/W3/H1)
    gemm256_k<2><<<g12 + DQBLK, 512, 0, stream>>>(Xb, W3, H1, MTOK, HID, DIM,
                                                  g12, w2c, w2a, W1);
    // out = h @ W2^T (W2 lives in W1's buffer), fp32 output
    gemm256_k<0><<<g3, 512, 0, stream>>>(H1, W1, (float*)d_out, MTOK, DIM, HID,
                                         g3, nullptr, nullptr, nullptr);
}

// Round 9
// 1113.343 us; speedup vs baseline: 1.4431x; 1.4431x over previous
//
#include <hip/hip_runtime.h>
#include <hip/hip_bf16.h>
#include <stdint.h>

// ---- problem dims (fixed by setup_inputs) ----
#define DIM   4096
#define HID   11008
#define MTOK  4096              // B*S = 2*2048
#define NELW  (HID * DIM)       // 45,088,768 elements per weight matrix

typedef __bf16 bf16x8 __attribute__((ext_vector_type(8)));
typedef float  f32x4  __attribute__((ext_vector_type(4)));
using gptr_t = const __attribute__((address_space(1))) void*;
using lptr_t = __attribute__((address_space(3))) void*;

__device__ __forceinline__ float bf2f(unsigned short u) {
    unsigned int t = ((unsigned int)u) << 16;
    float f; __builtin_memcpy(&f, &t, 4); return f;
}
__device__ __forceinline__ unsigned short f2bf(float f) {   // RNE
    unsigned int x; __builtin_memcpy(&x, &f, 4);
    x += 0x7fffu + ((x >> 16) & 1u);
    return (unsigned short)(x >> 16);
}

__device__ __constant__ float NF4_TAB[16] = {
    -1.0f, -0.6961928009986877f, -0.5250730514526367f, -0.39491748809814453f,
    -0.28444138169288635f, -0.18477343022823334f, -0.09105003625154495f, 0.0f,
    0.07958029955625534f, 0.16093020141124725f, 0.24611230194568634f,
    0.33791524171829224f, 0.44070982933044434f, 0.5626170039176941f,
    0.6989939212799072f, 1.0f};

// dequant 8 codes at element offset `base` (table via wave shfl from lanes 0-15)
__device__ __forceinline__ void dq8(const int* codes, const float* absmax,
                                    unsigned short* out, long base, float tv)
{
    int4 c0 = *(const int4*)(codes + base);
    int4 c1 = *(const int4*)(codes + base + 4);
    float s = absmax[base >> 6];
    union { uint4 q; unsigned short u[8]; } o;
    o.u[0] = f2bf(__shfl(tv, c0.x) * s);
    o.u[1] = f2bf(__shfl(tv, c0.y) * s);
    o.u[2] = f2bf(__shfl(tv, c0.z) * s);
    o.u[3] = f2bf(__shfl(tv, c0.w) * s);
    o.u[4] = f2bf(__shfl(tv, c1.x) * s);
    o.u[5] = f2bf(__shfl(tv, c1.y) * s);
    o.u[6] = f2bf(__shfl(tv, c1.z) * s);
    o.u[7] = f2bf(__shfl(tv, c1.w) * s);
    *(uint4*)(out + base) = o.q;
}

// preamble: blocks [0, 22016) dequant W1; blocks [22016, 30208) cast x->bf16
#define W1BLK 22016
#define PREBLK (W1BLK + (MTOK * DIM) / 2048)
__global__ __launch_bounds__(256) void pre_k(
    const int* __restrict__ w1c, const float* __restrict__ w1a,
    unsigned short* __restrict__ W1,
    const float* __restrict__ x, unsigned short* __restrict__ Xb)
{
    float tv = NF4_TAB[threadIdx.x & 15];
    if ((int)blockIdx.x < W1BLK) {
        long base = ((long)blockIdx.x * 256 + threadIdx.x) * 8;
        dq8(w1c, w1a, W1, base, tv);
    } else {
        long base = ((long)(blockIdx.x - W1BLK) * 256 + threadIdx.x) * 8;
        float4 a = *(const float4*)(x + base);
        float4 b = *(const float4*)(x + base + 4);
        union { uint4 q; unsigned short u[8]; } o;
        o.u[0] = f2bf(a.x); o.u[1] = f2bf(a.y); o.u[2] = f2bf(a.z); o.u[3] = f2bf(a.w);
        o.u[4] = f2bf(b.x); o.u[5] = f2bf(b.y); o.u[6] = f2bf(b.z); o.u[7] = f2bf(b.w);
        *(uint4*)(Xb + base) = o.q;
    }
}

// ============================================================================
// 256x256-tile 4-phase/K-tile GEMM — R7 core (16x16x32, runtime cur; R8's 2x
// unroll REVERTED: it spilled ~2.4KB/block-tile to scratch, WRITE_SIZE
// 179->283MB).  R9: ONE barrier per phase (the LD->MMA barrier removed).
//
// Single-barrier derivation (region lifetimes, all >=2 barriers between a
// region's last ds_read-drain and its overwriting STAGE; per-wave issue order
// and therefore the whole vmcnt ledger UNCHANGED from the r3/r4-verified
// version):  phase = {STAGE_next, ds_read_cur, MMA(lgkm-drains own reads),
// [vmcnt publish], BAR}.  A wave flows read->MFMA at its own pace, so one
// wave's MFMAs overlap another's ds_reads (cross-pipe overlap the 2-barrier
// lockstep was blocking: all-read-then-all-MMA).  Publishes: prologue
// vmcnt(4)+BAR (tile0); P3 vmcnt(6)+BAR (A[t+1]); P4 vmcnt(4)+BAR (B[t+1]).
// In-flight never <4 (T4).  Overwrite checks: B0[t+1] vs drain at t-1 P1
// (3 bars); B1[t+1] vs t-1 P3 (2 bars); A0[t+2] vs t P1 (2 bars); A1[t+2]
// vs t P2 (1 bar + barrier-pass implies drain).  Clamped tail dupes land in
// the dead opposite-parity buffer.
//
// Blocks >= ngemm run grid-stride NF4 dequant (dqc/dqa->dqo) -- tail fill;
// consumer is the NEXT dispatch (dispatch boundary = fence).
// MODE: 0 = f32 out, 1 = bf16 out, 2 = bf16 fused h=silu(Cout)*acc in-place.
// ============================================================================
template<int MODE>
__global__ __launch_bounds__(512, 2) void gemm256_k(
    const unsigned short* __restrict__ A, const unsigned short* __restrict__ B,
    void* __restrict__ Cout, int M, int N, int K, int ngemm,
    const int* __restrict__ dqc, const float* __restrict__ dqa,
    unsigned short* __restrict__ dqo)
{
    __shared__ __align__(16) unsigned short lds[2][2][2][128 * 64];

    const int tid = threadIdx.x;
    const int lane = tid & 63;

    if ((int)blockIdx.x >= ngemm) {          // ---- tail: grid-stride dequant
        if (!dqo) return;
        const int b = (int)blockIdx.x - ngemm;
        const int ndq = (int)gridDim.x - ngemm;
        const long stride = (long)ndq * 512 * 8;
        float tv = NF4_TAB[lane & 15];
        for (long base = ((long)b * 512 + tid) * 8; base < (long)NELW; base += stride)
            dq8(dqc, dqa, dqo, base, tv);
        return;
    }

    const int w = tid >> 6;
    const int wm = w >> 2, wn = w & 3;           // 2M x 4N wave grid
    const int lrow = lane & 15, hi = lane >> 4;
    const int key = lrow & 7;                    // read-side swizzle key

    const int nbm = M >> 8, nbn = N >> 8;
    const int cpx = (nbm * nbn) >> 3;            // ngemm%8==0 -> bijective
    int swz = ((int)blockIdx.x & 7) * cpx + ((int)blockIdx.x >> 3);
    const int bm = swz % nbm, bn = swz / nbm;    // bm fastest: B-panel reuse

    const long ldK = K;
    const int srow = tid >> 3;                   // 0..63 staging row
    const int scol = ((tid & 7) ^ (srow & 7)) * 8;   // pre-swizzled source col
    const unsigned short* gA = A + ((long)(bm * 256 + srow)) * ldK + scol;
    const unsigned short* gB = B + ((long)(bn * 256 + srow)) * ldK + scol;

    f32x4 acc[8][4];
    #pragma unroll
    for (int m = 0; m < 8; ++m)
        #pragma unroll
        for (int n = 0; n < 4; ++n) acc[m][n] = f32x4{0.f, 0.f, 0.f, 0.f};

    bf16x8 a0[4][2], a1[4][2], b0[2][2], b1[2][2];

    // stage half-tile h (0=A rows0-127, 1=A rows128-255, 2=B0, 3=B1) of K-tile
    auto STAGE = [&](int kt, int h, int b) {
        const unsigned short* src = ((h >> 1) ? gB : gA)
            + (long)((h & 1) * 128) * ldK + (long)kt * 64;
        char* dst = (char*)&lds[b][h >> 1][h & 1][0] + w * 1024;
        __builtin_amdgcn_global_load_lds((gptr_t)src, (lptr_t)dst, 16, 0, 0);
        __builtin_amdgcn_global_load_lds((gptr_t)(src + (long)64 * ldK),
                                         (lptr_t)(dst + 8192), 16, 0, 0);
    };
    // lane's A fragments: which=0 -> rows 0-63 of wave's half, 1 -> rows 64-127
    auto LDA = [&](bf16x8 (&fr)[4][2], int which, int b) {
        const unsigned short* base = &lds[b][0][wm][0];
        #pragma unroll
        for (int m = 0; m < 4; ++m)
            #pragma unroll
            for (int ks = 0; ks < 2; ++ks)
                fr[m][ks] = *(const bf16x8*)(base + (which * 64 + m * 16 + lrow) * 64
                                             + (((ks * 4 + hi) ^ key) * 8));
    };
    // lane's B fragments: which=0 -> n0..1, 1 -> n2..3
    auto LDB = [&](bf16x8 (&fr)[2][2], int which, int b) {
        const unsigned short* base = &lds[b][1][wn >> 1][0];
        #pragma unroll
        for (int n = 0; n < 2; ++n)
            #pragma unroll
            for (int ks = 0; ks < 2; ++ks)
                fr[n][ks] = *(const bf16x8*)(base + ((wn & 1) * 64 + (which * 2 + n) * 16 + lrow) * 64
                                             + (((ks * 4 + hi) ^ key) * 8));
    };
    auto MMA = [&](bf16x8 (&fa)[4][2], bf16x8 (&fb)[2][2], int mo, int no) {
        __builtin_amdgcn_s_setprio(1);
        #pragma unroll
        for (int m = 0; m < 4; ++m)
            #pragma unroll
            for (int n = 0; n < 2; ++n)
                #pragma unroll
                for (int ks = 0; ks < 2; ++ks)
                    acc[mo + m][no + n] = __builtin_amdgcn_mfma_f32_16x16x32_bf16(
                        fa[m][ks], fb[n][ks], acc[mo + m][no + n], 0, 0, 0);
        __builtin_amdgcn_s_setprio(0);
    };
    // s_barrier + sched fence for memory classes (ALU/VALU/SALU/MFMA may cross)
    #define BAR() do { __builtin_amdgcn_s_barrier(); \
                       __builtin_amdgcn_sched_barrier(0xF); } while (0)

    const int NT = K >> 6;
    // ---- prologue: tile0 fully + A-halves of tile1; publish tile0, THEN read
    STAGE(0, 0, 0); STAGE(0, 1, 0); STAGE(0, 2, 0); STAGE(0, 3, 0);
    STAGE(1, 0, 1); STAGE(1, 1, 1);
    asm volatile("s_waitcnt vmcnt(4)" ::: "memory");   // own tile0 loads landed
    BAR();                                             // ...and everyone else's
    LDA(a0, 0, 0);

    int cur = 0;
    for (int t = 0; t < NT - 1; ++t) {
        const int nb = cur ^ 1;
        const int tA = (t + 2 < NT) ? t + 2 : NT - 1;  // clamped: dupes land dead
        // P1: B[t] lower frags; issue B0[t+1]
        STAGE(t + 1, 2, nb);
        LDB(b0, 0, cur);
        MMA(a0, b0, 0, 0);
        BAR();
        // P2: A[t] upper frags; issue B1[t+1]
        STAGE(t + 1, 3, nb);
        LDA(a1, 1, cur);
        MMA(a1, b0, 4, 0);
        BAR();
        // P3: B[t] upper frags; issue A0[t+2]; publish A[t+1] (vmcnt 6)
        STAGE(tA, 0, cur);
        LDB(b1, 1, cur);
        MMA(a0, b1, 0, 2);
        asm volatile("s_waitcnt vmcnt(6)" ::: "memory");
        BAR();
        // P4: A[t+1] lower frags from next buf; issue A1[t+2]; publish B[t+1]
        STAGE(tA, 1, cur);
        LDA(a0, 0, nb);
        MMA(a1, b1, 4, 2);
        asm volatile("s_waitcnt vmcnt(4)" ::: "memory");
        BAR();
        cur = nb;
    }
    // ---- epilogue: last tile, fully published by final P3/P4 waits ----
    LDB(b0, 0, cur);
    MMA(a0, b0, 0, 0);
    LDA(a1, 1, cur);
    MMA(a1, b0, 4, 0);
    LDB(b1, 1, cur);
    MMA(a0, b1, 0, 2);
    MMA(a1, b1, 4, 2);
    #undef BAR

    // ---- C write.  C/D layout: col = lane&15, row = (lane>>4)*4 + reg ----
    const int grow = bm * 256 + wm * 128 + hi * 4;
    const int gcol = bn * 256 + wn * 64 + lrow;
    if (MODE == 0) {
        float* C = (float*)Cout;
        #pragma unroll
        for (int m = 0; m < 8; ++m)
            #pragma unroll
            for (int n = 0; n < 4; ++n)
                #pragma unroll
                for (int r = 0; r < 4; ++r)
                    C[(long)(grow + m * 16 + r) * N + gcol + n * 16] = acc[m][n][r];
    } else if (MODE == 1) {
        unsigned short* C = (unsigned short*)Cout;
        #pragma unroll
        for (int m = 0; m < 8; ++m)
            #pragma unroll
            for (int n = 0; n < 4; ++n)
                #pragma unroll
                for (int r = 0; r < 4; ++r)
                    C[(long)(grow + m * 16 + r) * N + gcol + n * 16] = f2bf(acc[m][n][r]);
    } else {
        // fused SwiGLU: C holds h1 (bf16); acc = h3. write silu(h1)*h3 in place
        unsigned short* C = (unsigned short*)Cout;
        #pragma unroll
        for (int m = 0; m < 8; ++m)
            #pragma unroll
            for (int n = 0; n < 4; ++n)
                #pragma unroll
                for (int r = 0; r < 4; ++r) {
                    long idx = (long)(grow + m * 16 + r) * N + gcol + n * 16;
                    float h1v = bf2f(C[idx]);
                    float g = h1v / (1.0f + __expf(-h1v));
                    C[idx] = f2bf(g * acc[m][n][r]);
                }
    }
}

// ---- workspace layout (bytes) ----
//  [0)          W1 bf16 (90,177,536)
//  [90177536)   W3 bf16 (90,177,536)  -- later reused for W2
//  [180355072)  x  bf16 (33,554,432)
//  [213909504)  h1 bf16 (90,177,536)  -- fused swiglu written in-place by GEMM2
//  total 304,087,040
#define WS_NEEDED 304087040UL
#define DQBLK 512     // tail dequant blocks appended to GEMM1/GEMM2 dispatches

extern "C" void kernel_launch(void* const* d_in, const int* in_sizes, int n_in,
                              void* d_out, int out_size, void* d_ws, size_t ws_size,
                              hipStream_t stream) {
    const float* x   = (const float*)d_in[0];
    const int*   w1c = (const int*)d_in[1];
    const float* w1a = (const float*)d_in[2];
    const int*   w2c = (const int*)d_in[3];
    const float* w2a = (const float*)d_in[4];
    const int*   w3c = (const int*)d_in[5];
    const float* w3a = (const float*)d_in[6];

    if (ws_size < WS_NEEDED) return;   // fail loudly via validation

    char* ws = (char*)d_ws;
    unsigned short* W1 = (unsigned short*)(ws);
    unsigned short* W3 = (unsigned short*)(ws + 90177536);   // also W2 later
    unsigned short* Xb = (unsigned short*)(ws + 180355072);
    unsigned short* H1 = (unsigned short*)(ws + 213909504);

    // preamble: W1 dequant + x cast (one dispatch)
    pre_k<<<PREBLK, 256, 0, stream>>>(w1c, w1a, W1, x, Xb);

    const int g12 = (MTOK / 256) * (HID / 256);   // 688
    const int g3  = (MTOK / 256) * (DIM / 256);   // 256

    // h1 = x @ W1^T; tail blocks dequant W3 -> consumed by NEXT dispatch
    gemm256_k<1><<<g12 + DQBLK, 512, 0, stream>>>(Xb, W1, H1, MTOK, HID, DIM,
                                                  g12, w3c, w3a, W3);
    // h = silu(h1) * (x @ W3^T) in-place; tail blocks dequant W2 into W1's buf
    // (GEMM1 retired at dispatch boundary; this dispatch reads only Xb/W3/H1)
    gemm256_k<2><<<g12 + DQBLK, 512, 0, stream>>>(Xb, W3, H1, MTOK, HID, DIM,
                                                  g12, w2c, w2a, W1);
    // out = h @ W2^T (W2 lives in W1's buffer), fp32 output
    gemm256_k<0><<<g3, 512, 0, stream>>>(H1, W1, (float*)d_out, MTOK, DIM, HID,
                                         g3, nullptr, nullptr, nullptr);
}

// Round 10
// 1103.845 us; speedup vs baseline: 1.4556x; 1.0086x over previous
//
#include <hip/hip_runtime.h>
#include <hip/hip_bf16.h>
#include <stdint.h>

// ---- problem dims (fixed by setup_inputs) ----
#define DIM   4096
#define HID   11008
#define MTOK  4096              // B*S = 2*2048
#define NELW  (HID * DIM)       // 45,088,768 elements per weight matrix

typedef __bf16 bf16x8 __attribute__((ext_vector_type(8)));
typedef float  f32x4  __attribute__((ext_vector_type(4)));
using gptr_t = const __attribute__((address_space(1))) void*;
using lptr_t = __attribute__((address_space(3))) void*;

__device__ __forceinline__ float bf2f(unsigned short u) {
    unsigned int t = ((unsigned int)u) << 16;
    float f; __builtin_memcpy(&f, &t, 4); return f;
}
__device__ __forceinline__ unsigned short f2bf(float f) {   // RNE
    unsigned int x; __builtin_memcpy(&x, &f, 4);
    x += 0x7fffu + ((x >> 16) & 1u);
    return (unsigned short)(x >> 16);
}

__device__ __constant__ float NF4_TAB[16] = {
    -1.0f, -0.6961928009986877f, -0.5250730514526367f, -0.39491748809814453f,
    -0.28444138169288635f, -0.18477343022823334f, -0.09105003625154495f, 0.0f,
    0.07958029955625534f, 0.16093020141124725f, 0.24611230194568634f,
    0.33791524171829224f, 0.44070982933044434f, 0.5626170039176941f,
    0.6989939212799072f, 1.0f};

// dequant 8 codes at element offset `base` (table via wave shfl from lanes 0-15)
__device__ __forceinline__ void dq8(const int* codes, const float* absmax,
                                    unsigned short* out, long base, float tv)
{
    int4 c0 = *(const int4*)(codes + base);
    int4 c1 = *(const int4*)(codes + base + 4);
    float s = absmax[base >> 6];
    union { uint4 q; unsigned short u[8]; } o;
    o.u[0] = f2bf(__shfl(tv, c0.x) * s);
    o.u[1] = f2bf(__shfl(tv, c0.y) * s);
    o.u[2] = f2bf(__shfl(tv, c0.z) * s);
    o.u[3] = f2bf(__shfl(tv, c0.w) * s);
    o.u[4] = f2bf(__shfl(tv, c1.x) * s);
    o.u[5] = f2bf(__shfl(tv, c1.y) * s);
    o.u[6] = f2bf(__shfl(tv, c1.z) * s);
    o.u[7] = f2bf(__shfl(tv, c1.w) * s);
    *(uint4*)(out + base) = o.q;
}

// preamble: blocks [0, 22016) dequant W1; blocks [22016, 30208) cast x->bf16
#define W1BLK 22016
#define PREBLK (W1BLK + (MTOK * DIM) / 2048)
__global__ __launch_bounds__(256) void pre_k(
    const int* __restrict__ w1c, const float* __restrict__ w1a,
    unsigned short* __restrict__ W1,
    const float* __restrict__ x, unsigned short* __restrict__ Xb)
{
    float tv = NF4_TAB[threadIdx.x & 15];
    if ((int)blockIdx.x < W1BLK) {
        long base = ((long)blockIdx.x * 256 + threadIdx.x) * 8;
        dq8(w1c, w1a, W1, base, tv);
    } else {
        long base = ((long)(blockIdx.x - W1BLK) * 256 + threadIdx.x) * 8;
        float4 a = *(const float4*)(x + base);
        float4 b = *(const float4*)(x + base + 4);
        union { uint4 q; unsigned short u[8]; } o;
        o.u[0] = f2bf(a.x); o.u[1] = f2bf(a.y); o.u[2] = f2bf(a.z); o.u[3] = f2bf(a.w);
        o.u[4] = f2bf(b.x); o.u[5] = f2bf(b.y); o.u[6] = f2bf(b.z); o.u[7] = f2bf(b.w);
        *(uint4*)(Xb + base) = o.q;
    }
}

// ============================================================================
// 256x256-tile 4-phase/K-tile GEMM — R9 core + R10: intra-wave read re-phasing.
//
// R9 cycle audit: 4884 cy/K-tile ≈ MFMA floor (2483) + DS floor (2304) -> the
// pipes were fully SERIALIZED (each phase's MFMA consumed that phase's reads,
// barriers aligned all waves).  R10: a1 is read in P1 (one phase before its
// P2 consumption), so P2's and P4's MFMA clusters depend only on prior-phase
// reads and run WHILE the DS pipe serves other phases' reads.  P1 (b0) and
// P3 (b1) keep a ~170cy same-phase dep (register-peak-neutral variant; the
// b1->P1 move would add +16 live VGPR and risk the 248/256 occupancy cliff).
//
// Window checks for the moved read (a1[t], region A1 of buffer cur):
//   published: t-1 P3 vmcnt(6)+BAR (covers A1[t], issued t-2 P4)  ✓ P1 read ok
//   (t=0: prologue vmcnt(4)+BAR publishes all of tile0)           ✓
//   overwritten: t P4's STAGE(t+2,1,cur) — 3 barriers after the P1 read,
//   reads drained by P2's consuming MFMA                          ✓
// STAGE issue order, vmcnt placement, barrier count: IDENTICAL to the
// r3/r4-verified ledger (prologue 12 issues, vmcnt(4); P3 vmcnt(6) publishes
// A[t+1]; P4 vmcnt(4) publishes B[t+1]; in-flight never <4).
//
// Blocks >= ngemm run grid-stride NF4 dequant (dqc/dqa->dqo) -- tail fill;
// consumer is the NEXT dispatch (dispatch boundary = fence).
// MODE: 0 = f32 out, 1 = bf16 out, 2 = bf16 fused h=silu(Cout)*acc in-place.
// ============================================================================
template<int MODE>
__global__ __launch_bounds__(512, 2) void gemm256_k(
    const unsigned short* __restrict__ A, const unsigned short* __restrict__ B,
    void* __restrict__ Cout, int M, int N, int K, int ngemm,
    const int* __restrict__ dqc, const float* __restrict__ dqa,
    unsigned short* __restrict__ dqo)
{
    __shared__ __align__(16) unsigned short lds[2][2][2][128 * 64];

    const int tid = threadIdx.x;
    const int lane = tid & 63;

    if ((int)blockIdx.x >= ngemm) {          // ---- tail: grid-stride dequant
        if (!dqo) return;
        const int b = (int)blockIdx.x - ngemm;
        const int ndq = (int)gridDim.x - ngemm;
        const long stride = (long)ndq * 512 * 8;
        float tv = NF4_TAB[lane & 15];
        for (long base = ((long)b * 512 + tid) * 8; base < (long)NELW; base += stride)
            dq8(dqc, dqa, dqo, base, tv);
        return;
    }

    const int w = tid >> 6;
    const int wm = w >> 2, wn = w & 3;           // 2M x 4N wave grid
    const int lrow = lane & 15, hi = lane >> 4;
    const int key = lrow & 7;                    // read-side swizzle key

    const int nbm = M >> 8, nbn = N >> 8;
    const int cpx = (nbm * nbn) >> 3;            // ngemm%8==0 -> bijective
    int swz = ((int)blockIdx.x & 7) * cpx + ((int)blockIdx.x >> 3);
    const int bm = swz % nbm, bn = swz / nbm;    // bm fastest: B-panel reuse

    const long ldK = K;
    const int srow = tid >> 3;                   // 0..63 staging row
    const int scol = ((tid & 7) ^ (srow & 7)) * 8;   // pre-swizzled source col
    const unsigned short* gA = A + ((long)(bm * 256 + srow)) * ldK + scol;
    const unsigned short* gB = B + ((long)(bn * 256 + srow)) * ldK + scol;

    f32x4 acc[8][4];
    #pragma unroll
    for (int m = 0; m < 8; ++m)
        #pragma unroll
        for (int n = 0; n < 4; ++n) acc[m][n] = f32x4{0.f, 0.f, 0.f, 0.f};

    bf16x8 a0[4][2], a1[4][2], b0[2][2], b1[2][2];

    // stage half-tile h (0=A rows0-127, 1=A rows128-255, 2=B0, 3=B1) of K-tile
    auto STAGE = [&](int kt, int h, int b) {
        const unsigned short* src = ((h >> 1) ? gB : gA)
            + (long)((h & 1) * 128) * ldK + (long)kt * 64;
        char* dst = (char*)&lds[b][h >> 1][h & 1][0] + w * 1024;
        __builtin_amdgcn_global_load_lds((gptr_t)src, (lptr_t)dst, 16, 0, 0);
        __builtin_amdgcn_global_load_lds((gptr_t)(src + (long)64 * ldK),
                                         (lptr_t)(dst + 8192), 16, 0, 0);
    };
    // lane's A fragments: which=0 -> rows 0-63 of wave's half, 1 -> rows 64-127
    auto LDA = [&](bf16x8 (&fr)[4][2], int which, int b) {
        const unsigned short* base = &lds[b][0][wm][0];
        #pragma unroll
        for (int m = 0; m < 4; ++m)
            #pragma unroll
            for (int ks = 0; ks < 2; ++ks)
                fr[m][ks] = *(const bf16x8*)(base + (which * 64 + m * 16 + lrow) * 64
                                             + (((ks * 4 + hi) ^ key) * 8));
    };
    // lane's B fragments: which=0 -> n0..1, 1 -> n2..3
    auto LDB = [&](bf16x8 (&fr)[2][2], int which, int b) {
        const unsigned short* base = &lds[b][1][wn >> 1][0];
        #pragma unroll
        for (int n = 0; n < 2; ++n)
            #pragma unroll
            for (int ks = 0; ks < 2; ++ks)
                fr[n][ks] = *(const bf16x8*)(base + ((wn & 1) * 64 + (which * 2 + n) * 16 + lrow) * 64
                                             + (((ks * 4 + hi) ^ key) * 8));
    };
    auto MMA = [&](bf16x8 (&fa)[4][2], bf16x8 (&fb)[2][2], int mo, int no) {
        __builtin_amdgcn_s_setprio(1);
        #pragma unroll
        for (int m = 0; m < 4; ++m)
            #pragma unroll
            for (int n = 0; n < 2; ++n)
                #pragma unroll
                for (int ks = 0; ks < 2; ++ks)
                    acc[mo + m][no + n] = __builtin_amdgcn_mfma_f32_16x16x32_bf16(
                        fa[m][ks], fb[n][ks], acc[mo + m][no + n], 0, 0, 0);
        __builtin_amdgcn_s_setprio(0);
    };
    // s_barrier + sched fence for memory classes (ALU/VALU/SALU/MFMA may cross)
    #define BAR() do { __builtin_amdgcn_s_barrier(); \
                       __builtin_amdgcn_sched_barrier(0xF); } while (0)

    const int NT = K >> 6;
    // ---- prologue: tile0 fully + A-halves of tile1; publish tile0, THEN read
    STAGE(0, 0, 0); STAGE(0, 1, 0); STAGE(0, 2, 0); STAGE(0, 3, 0);
    STAGE(1, 0, 1); STAGE(1, 1, 1);
    asm volatile("s_waitcnt vmcnt(4)" ::: "memory");   // own tile0 loads landed
    BAR();                                             // ...and everyone else's
    LDA(a0, 0, 0);

    int cur = 0;
    for (int t = 0; t < NT - 1; ++t) {
        const int nb = cur ^ 1;
        const int tA = (t + 2 < NT) ? t + 2 : NT - 1;  // clamped: dupes land dead
        // P1: read b0[t] AND a1[t] (a1 feeds P2); issue B0[t+1]
        STAGE(t + 1, 2, nb);
        LDB(b0, 0, cur);
        LDA(a1, 1, cur);
        MMA(a0, b0, 0, 0);
        BAR();
        // P2: no reads — MMA(a1,b0) runs on P1's reads while DS pipe is free
        STAGE(t + 1, 3, nb);
        MMA(a1, b0, 4, 0);
        BAR();
        // P3: read b1[t]; issue A0[t+2]; publish A[t+1] (vmcnt 6)
        STAGE(tA, 0, cur);
        LDB(b1, 1, cur);
        MMA(a0, b1, 0, 2);
        asm volatile("s_waitcnt vmcnt(6)" ::: "memory");
        BAR();
        // P4: read a0[t+1] (published at P3 barrier); MMA(a1,b1) on prior reads
        STAGE(tA, 1, cur);
        LDA(a0, 0, nb);
        MMA(a1, b1, 4, 2);
        asm volatile("s_waitcnt vmcnt(4)" ::: "memory");
        BAR();
        cur = nb;
    }
    // ---- epilogue: last tile, fully published by final P3/P4 waits ----
    LDB(b0, 0, cur);
    LDA(a1, 1, cur);
    MMA(a0, b0, 0, 0);
    MMA(a1, b0, 4, 0);
    LDB(b1, 1, cur);
    MMA(a0, b1, 0, 2);
    MMA(a1, b1, 4, 2);
    #undef BAR

    // ---- C write.  C/D layout: col = lane&15, row = (lane>>4)*4 + reg ----
    const int grow = bm * 256 + wm * 128 + hi * 4;
    const int gcol = bn * 256 + wn * 64 + lrow;
    if (MODE == 0) {
        float* C = (float*)Cout;
        #pragma unroll
        for (int m = 0; m < 8; ++m)
            #pragma unroll
            for (int n = 0; n < 4; ++n)
                #pragma unroll
                for (int r = 0; r < 4; ++r)
                    C[(long)(grow + m * 16 + r) * N + gcol + n * 16] = acc[m][n][r];
    } else if (MODE == 1) {
        unsigned short* C = (unsigned short*)Cout;
        #pragma unroll
        for (int m = 0; m < 8; ++m)
            #pragma unroll
            for (int n = 0; n < 4; ++n)
                #pragma unroll
                for (int r = 0; r < 4; ++r)
                    C[(long)(grow + m * 16 + r) * N + gcol + n * 16] = f2bf(acc[m][n][r]);
    } else {
        // fused SwiGLU: C holds h1 (bf16); acc = h3. write silu(h1)*h3 in place
        unsigned short* C = (unsigned short*)Cout;
        #pragma unroll
        for (int m = 0; m < 8; ++m)
            #pragma unroll
            for (int n = 0; n < 4; ++n)
                #pragma unroll
                for (int r = 0; r < 4; ++r) {
                    long idx = (long)(grow + m * 16 + r) * N + gcol + n * 16;
                    float h1v = bf2f(C[idx]);
                    float g = h1v / (1.0f + __expf(-h1v));
                    C[idx] = f2bf(g * acc[m][n][r]);
                }
    }
}

// ---- workspace layout (bytes) ----
//  [0)          W1 bf16 (90,177,536)
//  [90177536)   W3 bf16 (90,177,536)  -- later reused for W2
//  [180355072)  x  bf16 (33,554,432)
//  [213909504)  h1 bf16 (90,177,536)  -- fused swiglu written in-place by GEMM2
//  total 304,087,040
#define WS_NEEDED 304087040UL
#define DQBLK 512     // tail dequant blocks appended to GEMM1/GEMM2 dispatches

extern "C" void kernel_launch(void* const* d_in, const int* in_sizes, int n_in,
                              void* d_out, int out_size, void* d_ws, size_t ws_size,
                              hipStream_t stream) {
    const float* x   = (const float*)d_in[0];
    const int*   w1c = (const int*)d_in[1];
    const float* w1a = (const float*)d_in[2];
    const int*   w2c = (const int*)d_in[3];
    const float* w2a = (const float*)d_in[4];
    const int*   w3c = (const int*)d_in[5];
    const float* w3a = (const float*)d_in[6];

    if (ws_size < WS_NEEDED) return;   // fail loudly via validation

    char* ws = (char*)d_ws;
    unsigned short* W1 = (unsigned short*)(ws);
    unsigned short* W3 = (unsigned short*)(ws + 90177536);   // also W2 later
    unsigned short* Xb = (unsigned short*)(ws + 180355072);
    unsigned short* H1 = (unsigned short*)(ws + 213909504);

    // preamble: W1 dequant + x cast (one dispatch)
    pre_k<<<PREBLK, 256, 0, stream>>>(w1c, w1a, W1, x, Xb);

    const int g12 = (MTOK / 256) * (HID / 256);   // 688
    const int g3  = (MTOK / 256) * (DIM / 256);   // 256

    // h1 = x @ W1^T; tail blocks dequant W3 -> consumed by NEXT dispatch
    gemm256_k<1><<<g12 + DQBLK, 512, 0, stream>>>(Xb, W1, H1, MTOK, HID, DIM,
                                                  g12, w3c, w3a, W3);
    // h = silu(h1) * (x @ W3^T) in-place; tail blocks dequant W2 into W1's buf
    // (GEMM1 retired at dispatch boundary; this dispatch reads only Xb/W3/H1)
    gemm256_k<2><<<g12 + DQBLK, 512, 0, stream>>>(Xb, W3, H1, MTOK, HID, DIM,
                                                  g12, w2c, w2a, W1);
    // out = h @ W2^T (W2 lives in W1's buffer), fp32 output
    gemm256_k<0><<<g3, 512, 0, stream>>>(H1, W1, (float*)d_out, MTOK, DIM, HID,
                                         g3, nullptr, nullptr, nullptr);
}